// Round 1
// baseline (399.268 us; speedup 1.0000x reference)
//
#include <hip/hip_runtime.h>
#include <math.h>

// SDF loss: out = [loss(1), sdf_values(B*N), se3(B*16)]  (float32)
// G is fixed at 256 so flat grid index = (x<<16)|(y<<8)|z.

__global__ void pose_kernel(const float* __restrict__ pose_delta,  // B*6
                            const float* __restrict__ pose_init,   // B*16
                            float* __restrict__ out,               // d_out
                            float* __restrict__ rt,                // ws: B*12
                            int B, long long se3_off)
{
    int b = blockIdx.x * blockDim.x + threadIdx.x;
    if (b == 0) out[0] = 0.0f;   // zero the loss accumulator (stream-ordered before sdf_kernel)
    if (b >= B) return;

    const float* d = pose_delta + b * 6;
    float ux = d[0], uy = d[1], uz = d[2];
    float wx = d[3], wy = d[4], wz = d[5];
    float th2 = wx*wx + wy*wy + wz*wz;
    float th  = sqrtf(th2);
    float A, Bc, Cc;
    if (th < 1e-6f) {
        A  = 1.0f - th2 * (1.0f/6.0f);
        Bc = 0.5f - th2 * (1.0f/24.0f);
        Cc = (1.0f/6.0f) - th2 * (1.0f/120.0f);
    } else {
        float sn = sinf(th), cs = cosf(th);
        A  = sn / th;
        Bc = (1.0f - cs) / th2;
        Cc = (th - sn) / (th2 * th);
    }
    float K[3][3]  = {{0.f,-wz,wy},{wz,0.f,-wx},{-wy,wx,0.f}};
    float K2[3][3];
    #pragma unroll
    for (int i = 0; i < 3; i++)
        #pragma unroll
        for (int j = 0; j < 3; j++) {
            float s = 0.f;
            #pragma unroll
            for (int k = 0; k < 3; k++) s += K[i][k] * K[k][j];
            K2[i][j] = s;
        }
    float R[3][3], V[3][3];
    #pragma unroll
    for (int i = 0; i < 3; i++)
        #pragma unroll
        for (int j = 0; j < 3; j++) {
            float I = (i == j) ? 1.f : 0.f;
            R[i][j] = I + A  * K[i][j] + Bc * K2[i][j];
            V[i][j] = I + Bc * K[i][j] + Cc * K2[i][j];
        }
    float tt[3];
    #pragma unroll
    for (int i = 0; i < 3; i++)
        tt[i] = V[i][0]*ux + V[i][1]*uy + V[i][2]*uz;

    // M = [R|t; 0 0 0 1] @ pose_init[b]
    const float* P = pose_init + b * 16;
    float M[3][4];
    #pragma unroll
    for (int i = 0; i < 3; i++)
        #pragma unroll
        for (int j = 0; j < 4; j++)
            M[i][j] = R[i][0]*P[0*4+j] + R[i][1]*P[1*4+j] + R[i][2]*P[2*4+j] + tt[i]*P[3*4+j];

    float* o = out + se3_off + (long long)b * 16;
    #pragma unroll
    for (int i = 0; i < 3; i++)
        #pragma unroll
        for (int j = 0; j < 4; j++) o[i*4+j] = M[i][j];
    o[12] = P[12]; o[13] = P[13]; o[14] = P[14]; o[15] = P[15];

    float* r = rt + b * 12;
    #pragma unroll
    for (int i = 0; i < 3; i++) {
        r[i*4+0] = M[i][0]; r[i*4+1] = M[i][1];
        r[i*4+2] = M[i][2]; r[i*4+3] = M[i][3];
    }
}

__global__ __launch_bounds__(256)
void sdf_kernel(const float* __restrict__ grid,     // 256^3
                const float* __restrict__ limits,   // 6
                const float* __restrict__ points,   // N*3
                const float* __restrict__ rt,       // B*12
                float* __restrict__ out,            // [loss, sdf(B*N), ...]
                int N)
{
    const int b = blockIdx.y;
    const int n = blockIdx.x * 256 + threadIdx.x;

    // block-uniform pose row (compiler scalarizes these)
    const float* m = rt + b * 12;
    float m00=m[0], m01=m[1], m02=m[2],  m03=m[3];
    float m10=m[4], m11=m[5], m12=m[6],  m13=m[7];
    float m20=m[8], m21=m[9], m22=m[10], m23=m[11];
    float lo0=limits[0], lo1=limits[1], lo2=limits[2];
    float hi0=limits[3], hi1=limits[4], hi2=limits[5];
    float s0 = 255.0f/(hi0-lo0), s1 = 255.0f/(hi1-lo1), s2 = 255.0f/(hi2-lo2);

    float val = 0.0f;
    if (n < N) {
        float px = points[n*3+0], py = points[n*3+1], pz = points[n*3+2];
        float x = m00*px + m01*py + m02*pz + m03;
        float y = m10*px + m11*py + m12*pz + m13;
        float z = m20*px + m21*py + m22*pz + m23;
        float u0 = (x - lo0) * s0;
        float u1 = (y - lo1) * s1;
        float u2 = (z - lo2) * s2;
        u0 = fminf(fmaxf(u0, 0.f), 254.9999f);
        u1 = fminf(fmaxf(u1, 0.f), 254.9999f);
        u2 = fminf(fmaxf(u2, 0.f), 254.9999f);
        int x0 = (int)u0, y0 = (int)u1, z0 = (int)u2;   // floor (u >= 0)
        float fx = u0 - (float)x0, fy = u1 - (float)y0, fz = u2 - (float)z0;
        int x1 = min(x0 + 1, 255), y1 = min(y0 + 1, 255), z1 = min(z0 + 1, 255);

        int bx0 = x0 << 16, bx1 = x1 << 16;
        int by0 = y0 << 8,  by1 = y1 << 8;
        float g000 = grid[bx0|by0|z0], g100 = grid[bx1|by0|z0];
        float g010 = grid[bx0|by1|z0], g110 = grid[bx1|by1|z0];
        float g001 = grid[bx0|by0|z1], g101 = grid[bx1|by0|z1];
        float g011 = grid[bx0|by1|z1], g111 = grid[bx1|by1|z1];

        float c00 = g000*(1.f-fx) + g100*fx;
        float c10 = g010*(1.f-fx) + g110*fx;
        float c01 = g001*(1.f-fx) + g101*fx;
        float c11 = g011*(1.f-fx) + g111*fx;
        float c0  = c00*(1.f-fy) + c10*fy;
        float c1  = c01*(1.f-fy) + c11*fy;
        float v   = c0*(1.f-fz) + c1*fz;

        out[1 + (size_t)b * N + n] = v;
        val = v * v;
    }

    // wave64 shuffle reduce -> LDS -> one atomic per block
    #pragma unroll
    for (int off = 32; off > 0; off >>= 1) val += __shfl_down(val, off, 64);
    __shared__ float sm[4];
    int lane = threadIdx.x & 63, wid = threadIdx.x >> 6;
    if (lane == 0) sm[wid] = val;
    __syncthreads();
    if (threadIdx.x == 0)
        atomicAdd(out, 0.5f * (sm[0] + sm[1] + sm[2] + sm[3]));
}

extern "C" void kernel_launch(void* const* d_in, const int* in_sizes, int n_in,
                              void* d_out, int out_size, void* d_ws, size_t ws_size,
                              hipStream_t stream) {
    const float* pose_delta = (const float*)d_in[0];
    const float* pose_init  = (const float*)d_in[1];
    const float* grid       = (const float*)d_in[2];
    const float* limits     = (const float*)d_in[3];
    const float* points     = (const float*)d_in[4];
    float* out = (float*)d_out;
    float* rt  = (float*)d_ws;

    int B = in_sizes[0] / 6;
    int N = in_sizes[4] / 3;
    long long se3_off = 1 + (long long)B * N;

    pose_kernel<<<1, ((B + 63) / 64) * 64, 0, stream>>>(pose_delta, pose_init, out, rt, B, se3_off);

    dim3 g((N + 255) / 256, B);
    sdf_kernel<<<g, 256, 0, stream>>>(grid, limits, points, rt, out, N);
}

// Round 2
// 398.291 us; speedup vs baseline: 1.0025x; 1.0025x over previous
//
#include <hip/hip_runtime.h>
#include <hip/hip_fp16.h>
#include <math.h>

// SDF loss: out = [loss(1), sdf_values(B*N), se3(B*16)]  (float32)
// G fixed at 256: flat grid index = (x<<16)|(y<<8)|z.
//
// Fast path: pack all 8 cell corners into one fp16x8 (16B) table entry so the
// sample kernel does ONE dwordx4 gather per point instead of 8 scalar gathers.

__global__ void pose_kernel(const float* __restrict__ pose_delta,  // B*6
                            const float* __restrict__ pose_init,   // B*16
                            float* __restrict__ out,               // d_out
                            float* __restrict__ rt,                // ws: B*12
                            int B, long long se3_off)
{
    int b = blockIdx.x * blockDim.x + threadIdx.x;
    if (b == 0) out[0] = 0.0f;   // needed by fallback (atomic) path; overwritten by reduce in fast path
    if (b >= B) return;

    const float* d = pose_delta + b * 6;
    float ux = d[0], uy = d[1], uz = d[2];
    float wx = d[3], wy = d[4], wz = d[5];
    float th2 = wx*wx + wy*wy + wz*wz;
    float th  = sqrtf(th2);
    float A, Bc, Cc;
    if (th < 1e-6f) {
        A  = 1.0f - th2 * (1.0f/6.0f);
        Bc = 0.5f - th2 * (1.0f/24.0f);
        Cc = (1.0f/6.0f) - th2 * (1.0f/120.0f);
    } else {
        float sn = sinf(th), cs = cosf(th);
        A  = sn / th;
        Bc = (1.0f - cs) / th2;
        Cc = (th - sn) / (th2 * th);
    }
    float K[3][3]  = {{0.f,-wz,wy},{wz,0.f,-wx},{-wy,wx,0.f}};
    float K2[3][3];
    #pragma unroll
    for (int i = 0; i < 3; i++)
        #pragma unroll
        for (int j = 0; j < 3; j++) {
            float s = 0.f;
            #pragma unroll
            for (int k = 0; k < 3; k++) s += K[i][k] * K[k][j];
            K2[i][j] = s;
        }
    float R[3][3], V[3][3];
    #pragma unroll
    for (int i = 0; i < 3; i++)
        #pragma unroll
        for (int j = 0; j < 3; j++) {
            float I = (i == j) ? 1.f : 0.f;
            R[i][j] = I + A  * K[i][j] + Bc * K2[i][j];
            V[i][j] = I + Bc * K[i][j] + Cc * K2[i][j];
        }
    float tt[3];
    #pragma unroll
    for (int i = 0; i < 3; i++)
        tt[i] = V[i][0]*ux + V[i][1]*uy + V[i][2]*uz;

    const float* P = pose_init + b * 16;
    float M[3][4];
    #pragma unroll
    for (int i = 0; i < 3; i++)
        #pragma unroll
        for (int j = 0; j < 4; j++)
            M[i][j] = R[i][0]*P[0*4+j] + R[i][1]*P[1*4+j] + R[i][2]*P[2*4+j] + tt[i]*P[3*4+j];

    float* o = out + se3_off + (long long)b * 16;
    #pragma unroll
    for (int i = 0; i < 3; i++)
        #pragma unroll
        for (int j = 0; j < 4; j++) o[i*4+j] = M[i][j];
    o[12] = P[12]; o[13] = P[13]; o[14] = P[14]; o[15] = P[15];

    float* r = rt + b * 12;
    #pragma unroll
    for (int i = 0; i < 3; i++) {
        r[i*4+0] = M[i][0]; r[i*4+1] = M[i][1];
        r[i*4+2] = M[i][2]; r[i*4+3] = M[i][3];
    }
}

// Build fp16x8 corner table: tbl[idx] holds corners (dx,dy,dz) of cell idx,
// clamps baked in. Entry layout: x=(e000,e001) y=(e010,e011) z=(e100,e101) w=(e110,e111).
__global__ __launch_bounds__(256)
void pack_kernel(const float* __restrict__ g, uint4* __restrict__ tbl)
{
    int idx = blockIdx.x * 256 + threadIdx.x;
    int z = idx & 255, y = (idx >> 8) & 255, x = (idx >> 16) & 255;
    int xs = (x < 255) ? 65536 : 0;
    int ys = (y < 255) ? 256   : 0;
    int zs = (z < 255) ? 1     : 0;
    const float* p = g + idx;
    float e000 = p[0],       e001 = p[zs];
    float e010 = p[ys],      e011 = p[ys + zs];
    float e100 = p[xs],      e101 = p[xs + zs];
    float e110 = p[xs + ys], e111 = p[xs + ys + zs];
    uint4 u;
    __half2 h;
    h = __floats2half2_rn(e000, e001); u.x = *(unsigned int*)&h;
    h = __floats2half2_rn(e010, e011); u.y = *(unsigned int*)&h;
    h = __floats2half2_rn(e100, e101); u.z = *(unsigned int*)&h;
    h = __floats2half2_rn(e110, e111); u.w = *(unsigned int*)&h;
    tbl[idx] = u;
}

__global__ __launch_bounds__(256)
void sdf_packed(const uint4* __restrict__ tbl,
                const float* __restrict__ limits,
                const float* __restrict__ points,
                const float* __restrict__ rt,
                float* __restrict__ sdf_out,     // out+1
                float* __restrict__ partials,    // ws
                int N)
{
    const int b = blockIdx.y;
    const int n = blockIdx.x * 256 + threadIdx.x;

    const float* m = rt + b * 12;
    float m00=m[0], m01=m[1], m02=m[2],  m03=m[3];
    float m10=m[4], m11=m[5], m12=m[6],  m13=m[7];
    float m20=m[8], m21=m[9], m22=m[10], m23=m[11];
    float lo0=limits[0], lo1=limits[1], lo2=limits[2];
    float hi0=limits[3], hi1=limits[4], hi2=limits[5];
    float s0 = 255.0f/(hi0-lo0), s1 = 255.0f/(hi1-lo1), s2 = 255.0f/(hi2-lo2);

    float val = 0.0f;
    if (n < N) {
        float px = points[n*3+0], py = points[n*3+1], pz = points[n*3+2];
        float x = m00*px + m01*py + m02*pz + m03;
        float y = m10*px + m11*py + m12*pz + m13;
        float z = m20*px + m21*py + m22*pz + m23;
        float u0 = fminf(fmaxf((x - lo0) * s0, 0.f), 254.9999f);
        float u1 = fminf(fmaxf((y - lo1) * s1, 0.f), 254.9999f);
        float u2 = fminf(fmaxf((z - lo2) * s2, 0.f), 254.9999f);
        int x0 = (int)u0, y0 = (int)u1, z0 = (int)u2;
        float fx = u0 - (float)x0, fy = u1 - (float)y0, fz = u2 - (float)z0;

        uint4 u = tbl[(x0 << 16) | (y0 << 8) | z0];
        float2 f00 = __half22float2(*(__half2*)&u.x);
        float2 f01 = __half22float2(*(__half2*)&u.y);
        float2 f10 = __half22float2(*(__half2*)&u.z);
        float2 f11 = __half22float2(*(__half2*)&u.w);
        float c00 = f00.x + (f00.y - f00.x) * fz;
        float c01 = f01.x + (f01.y - f01.x) * fz;
        float c10 = f10.x + (f10.y - f10.x) * fz;
        float c11 = f11.x + (f11.y - f11.x) * fz;
        float b0  = c00 + (c01 - c00) * fy;
        float b1  = c10 + (c11 - c10) * fy;
        float v   = b0  + (b1  - b0 ) * fx;

        sdf_out[(size_t)b * N + n] = v;
        val = v * v;
    }

    #pragma unroll
    for (int off = 32; off > 0; off >>= 1) val += __shfl_down(val, off, 64);
    __shared__ float sm[4];
    int lane = threadIdx.x & 63, wid = threadIdx.x >> 6;
    if (lane == 0) sm[wid] = val;
    __syncthreads();
    if (threadIdx.x == 0)
        partials[(size_t)b * gridDim.x + blockIdx.x] = sm[0] + sm[1] + sm[2] + sm[3];
}

__global__ __launch_bounds__(1024)
void reduce_kernel(const float* __restrict__ partials, int n, float* __restrict__ out)
{
    float s = 0.f;
    for (int i = threadIdx.x; i < n; i += 1024) s += partials[i];
    #pragma unroll
    for (int off = 32; off > 0; off >>= 1) s += __shfl_down(s, off, 64);
    __shared__ float sm[16];
    int lane = threadIdx.x & 63, wid = threadIdx.x >> 6;
    if (lane == 0) sm[wid] = s;
    __syncthreads();
    if (threadIdx.x == 0) {
        float t = 0.f;
        #pragma unroll
        for (int i = 0; i < 16; i++) t += sm[i];
        out[0] = 0.5f * t;
    }
}

// Fallback (round-1) path: direct 8-gather sampling with atomic loss.
__global__ __launch_bounds__(256)
void sdf_kernel(const float* __restrict__ grid,
                const float* __restrict__ limits,
                const float* __restrict__ points,
                const float* __restrict__ rt,
                float* __restrict__ out, int N)
{
    const int b = blockIdx.y;
    const int n = blockIdx.x * 256 + threadIdx.x;
    const float* m = rt + b * 12;
    float m00=m[0], m01=m[1], m02=m[2],  m03=m[3];
    float m10=m[4], m11=m[5], m12=m[6],  m13=m[7];
    float m20=m[8], m21=m[9], m22=m[10], m23=m[11];
    float lo0=limits[0], lo1=limits[1], lo2=limits[2];
    float hi0=limits[3], hi1=limits[4], hi2=limits[5];
    float s0 = 255.0f/(hi0-lo0), s1 = 255.0f/(hi1-lo1), s2 = 255.0f/(hi2-lo2);

    float val = 0.0f;
    if (n < N) {
        float px = points[n*3+0], py = points[n*3+1], pz = points[n*3+2];
        float x = m00*px + m01*py + m02*pz + m03;
        float y = m10*px + m11*py + m12*pz + m13;
        float z = m20*px + m21*py + m22*pz + m23;
        float u0 = fminf(fmaxf((x - lo0) * s0, 0.f), 254.9999f);
        float u1 = fminf(fmaxf((y - lo1) * s1, 0.f), 254.9999f);
        float u2 = fminf(fmaxf((z - lo2) * s2, 0.f), 254.9999f);
        int x0 = (int)u0, y0 = (int)u1, z0 = (int)u2;
        float fx = u0 - (float)x0, fy = u1 - (float)y0, fz = u2 - (float)z0;
        int x1 = min(x0 + 1, 255), y1 = min(y0 + 1, 255), z1 = min(z0 + 1, 255);
        int bx0 = x0 << 16, bx1 = x1 << 16;
        int by0 = y0 << 8,  by1 = y1 << 8;
        float g000 = grid[bx0|by0|z0], g100 = grid[bx1|by0|z0];
        float g010 = grid[bx0|by1|z0], g110 = grid[bx1|by1|z0];
        float g001 = grid[bx0|by0|z1], g101 = grid[bx1|by0|z1];
        float g011 = grid[bx0|by1|z1], g111 = grid[bx1|by1|z1];
        float c00 = g000*(1.f-fx) + g100*fx;
        float c10 = g010*(1.f-fx) + g110*fx;
        float c01 = g001*(1.f-fx) + g101*fx;
        float c11 = g011*(1.f-fx) + g111*fx;
        float c0  = c00*(1.f-fy) + c10*fy;
        float c1  = c01*(1.f-fy) + c11*fy;
        float v   = c0*(1.f-fz) + c1*fz;
        out[1 + (size_t)b * N + n] = v;
        val = v * v;
    }
    #pragma unroll
    for (int off = 32; off > 0; off >>= 1) val += __shfl_down(val, off, 64);
    __shared__ float sm[4];
    int lane = threadIdx.x & 63, wid = threadIdx.x >> 6;
    if (lane == 0) sm[wid] = val;
    __syncthreads();
    if (threadIdx.x == 0)
        atomicAdd(out, 0.5f * (sm[0] + sm[1] + sm[2] + sm[3]));
}

extern "C" void kernel_launch(void* const* d_in, const int* in_sizes, int n_in,
                              void* d_out, int out_size, void* d_ws, size_t ws_size,
                              hipStream_t stream) {
    const float* pose_delta = (const float*)d_in[0];
    const float* pose_init  = (const float*)d_in[1];
    const float* grid       = (const float*)d_in[2];
    const float* limits     = (const float*)d_in[3];
    const float* points     = (const float*)d_in[4];
    float* out = (float*)d_out;

    int B = in_sizes[0] / 6;
    int N = in_sizes[4] / 3;
    long long se3_off = 1 + (long long)B * N;

    // ws layout: [0, 3KB) rt | [4KB, 1MB) partials | [1MB, +268MB) corner table
    const size_t TBL_OFF = 1u << 20;
    const size_t tbl_bytes = (size_t)(1 << 24) * 16;
    float* rt       = (float*)d_ws;
    float* partials = (float*)((char*)d_ws + 4096);
    uint4* tbl      = (uint4*)((char*)d_ws + TBL_OFF);

    pose_kernel<<<1, ((B + 63) / 64) * 64, 0, stream>>>(pose_delta, pose_init, out, rt, B, se3_off);

    bool fast = (in_sizes[2] == (1 << 24)) && (ws_size >= TBL_OFF + tbl_bytes);
    dim3 g((N + 255) / 256, B);
    if (fast) {
        pack_kernel<<<1 << 16, 256, 0, stream>>>(grid, tbl);
        sdf_packed<<<g, 256, 0, stream>>>(tbl, limits, points, rt, out + 1, partials, N);
        reduce_kernel<<<1, 1024, 0, stream>>>(partials, B * ((N + 255) / 256), out);
    } else {
        sdf_kernel<<<g, 256, 0, stream>>>(grid, limits, points, rt, out, N);
    }
}

// Round 3
// 188.254 us; speedup vs baseline: 2.1209x; 2.1157x over previous
//
#include <hip/hip_runtime.h>
#include <hip/hip_fp16.h>
#include <math.h>

// SDF loss: out = [loss(1), sdf_values(B*N), se3(B*16)]  (float32)
// G fixed at 256: flat grid index = (x<<16)|(y<<8)|z.
// Note: u is clamped to <= 254.9999 so x0,y0,z0 <= 254 and x1,y1,z1 <= 255
// (the reference's min(i0+1,255) never binds).
//
// ws layout: [0,3KB) rt | [4KB,~104KB) partials | [128KB, ...) table
//   Tier A (ws >= ~255.2MB): fp16x8 corner table, 255*65536 entries * 16B.
//                            ONE dwordx4 gather per point.
//   Tier C (ws >= ~33.8MB):  fp16 grid in 2x2x8 bricks (one 64B line per brick).
//                            8 ushort gathers, ~2.5 distinct lines/point, 32MB footprint.
//   else: direct fp32 fallback (round-1 path).

__global__ void pose_kernel(const float* __restrict__ pose_delta,  // B*6
                            const float* __restrict__ pose_init,   // B*16
                            float* __restrict__ out,               // d_out
                            float* __restrict__ rt,                // ws: B*12
                            int B, long long se3_off)
{
    int b = blockIdx.x * blockDim.x + threadIdx.x;
    if (b == 0) out[0] = 0.0f;   // for fallback (atomic) path; overwritten by reduce in fast paths
    if (b >= B) return;

    const float* d = pose_delta + b * 6;
    float ux = d[0], uy = d[1], uz = d[2];
    float wx = d[3], wy = d[4], wz = d[5];
    float th2 = wx*wx + wy*wy + wz*wz;
    float th  = sqrtf(th2);
    float A, Bc, Cc;
    if (th < 1e-6f) {
        A  = 1.0f - th2 * (1.0f/6.0f);
        Bc = 0.5f - th2 * (1.0f/24.0f);
        Cc = (1.0f/6.0f) - th2 * (1.0f/120.0f);
    } else {
        float sn = sinf(th), cs = cosf(th);
        A  = sn / th;
        Bc = (1.0f - cs) / th2;
        Cc = (th - sn) / (th2 * th);
    }
    float K[3][3]  = {{0.f,-wz,wy},{wz,0.f,-wx},{-wy,wx,0.f}};
    float K2[3][3];
    #pragma unroll
    for (int i = 0; i < 3; i++)
        #pragma unroll
        for (int j = 0; j < 3; j++) {
            float s = 0.f;
            #pragma unroll
            for (int k = 0; k < 3; k++) s += K[i][k] * K[k][j];
            K2[i][j] = s;
        }
    float R[3][3], V[3][3];
    #pragma unroll
    for (int i = 0; i < 3; i++)
        #pragma unroll
        for (int j = 0; j < 3; j++) {
            float I = (i == j) ? 1.f : 0.f;
            R[i][j] = I + A  * K[i][j] + Bc * K2[i][j];
            V[i][j] = I + Bc * K[i][j] + Cc * K2[i][j];
        }
    float tt[3];
    #pragma unroll
    for (int i = 0; i < 3; i++)
        tt[i] = V[i][0]*ux + V[i][1]*uy + V[i][2]*uz;

    const float* P = pose_init + b * 16;
    float M[3][4];
    #pragma unroll
    for (int i = 0; i < 3; i++)
        #pragma unroll
        for (int j = 0; j < 4; j++)
            M[i][j] = R[i][0]*P[0*4+j] + R[i][1]*P[1*4+j] + R[i][2]*P[2*4+j] + tt[i]*P[3*4+j];

    float* o = out + se3_off + (long long)b * 16;
    #pragma unroll
    for (int i = 0; i < 3; i++)
        #pragma unroll
        for (int j = 0; j < 4; j++) o[i*4+j] = M[i][j];
    o[12] = P[12]; o[13] = P[13]; o[14] = P[14]; o[15] = P[15];

    float* r = rt + b * 12;
    #pragma unroll
    for (int i = 0; i < 3; i++) {
        r[i*4+0] = M[i][0]; r[i*4+1] = M[i][1];
        r[i*4+2] = M[i][2]; r[i*4+3] = M[i][3];
    }
}

// ---------------- Tier A: fp16x8 corner table, 1 gather/point ----------------
// tbl[(x<<16)|(y<<8)|z], x in [0,254]. Entry: .x=(e000,e001) .y=(e010,e011)
// .z=(e100,e101) .w=(e110,e111), pairs packed low=z0 high=z1.
__global__ __launch_bounds__(256)
void pack_a(const float* __restrict__ g, uint4* __restrict__ tbl)
{
    int idx = blockIdx.x * 256 + threadIdx.x;   // < 255*65536, x = idx>>16 <= 254
    int z = idx & 255, y = (idx >> 8) & 255;
    int ys = (y < 255) ? 256 : 0;
    int zs = (z < 255) ? 1   : 0;
    const float* p = g + idx;
    float e000 = p[0],          e001 = p[zs];
    float e010 = p[ys],         e011 = p[ys + zs];
    float e100 = p[65536],      e101 = p[65536 + zs];
    float e110 = p[65536 + ys], e111 = p[65536 + ys + zs];
    uint4 u;
    __half2 h;
    h = __floats2half2_rn(e000, e001); u.x = *(unsigned int*)&h;
    h = __floats2half2_rn(e010, e011); u.y = *(unsigned int*)&h;
    h = __floats2half2_rn(e100, e101); u.z = *(unsigned int*)&h;
    h = __floats2half2_rn(e110, e111); u.w = *(unsigned int*)&h;
    tbl[idx] = u;
}

__global__ __launch_bounds__(256)
void sdf_a(const uint4* __restrict__ tbl,
           const float* __restrict__ limits,
           const float* __restrict__ points,
           const float* __restrict__ rt,
           float* __restrict__ sdf_out,     // out+1
           float* __restrict__ partials,    // ws+4KB
           int N)
{
    const int b = blockIdx.y;
    const int n = blockIdx.x * 256 + threadIdx.x;

    const float* m = rt + b * 12;
    float m00=m[0], m01=m[1], m02=m[2],  m03=m[3];
    float m10=m[4], m11=m[5], m12=m[6],  m13=m[7];
    float m20=m[8], m21=m[9], m22=m[10], m23=m[11];
    float lo0=limits[0], lo1=limits[1], lo2=limits[2];
    float hi0=limits[3], hi1=limits[4], hi2=limits[5];
    float s0 = 255.0f/(hi0-lo0), s1 = 255.0f/(hi1-lo1), s2 = 255.0f/(hi2-lo2);

    float val = 0.0f;
    if (n < N) {
        float px = points[n*3+0], py = points[n*3+1], pz = points[n*3+2];
        float x = m00*px + m01*py + m02*pz + m03;
        float y = m10*px + m11*py + m12*pz + m13;
        float z = m20*px + m21*py + m22*pz + m23;
        float u0 = fminf(fmaxf((x - lo0) * s0, 0.f), 254.9999f);
        float u1 = fminf(fmaxf((y - lo1) * s1, 0.f), 254.9999f);
        float u2 = fminf(fmaxf((z - lo2) * s2, 0.f), 254.9999f);
        int x0 = (int)u0, y0 = (int)u1, z0 = (int)u2;
        float fx = u0 - (float)x0, fy = u1 - (float)y0, fz = u2 - (float)z0;

        uint4 u = tbl[(x0 << 16) | (y0 << 8) | z0];
        float2 f00 = __half22float2(*(__half2*)&u.x);
        float2 f01 = __half22float2(*(__half2*)&u.y);
        float2 f10 = __half22float2(*(__half2*)&u.z);
        float2 f11 = __half22float2(*(__half2*)&u.w);
        float c00 = f00.x + (f00.y - f00.x) * fz;   // lerp z at (x0,y0)
        float c01 = f01.x + (f01.y - f01.x) * fz;   // (x0,y1)
        float c10 = f10.x + (f10.y - f10.x) * fz;   // (x1,y0)
        float c11 = f11.x + (f11.y - f11.x) * fz;   // (x1,y1)
        float b0  = c00 + (c01 - c00) * fy;
        float b1  = c10 + (c11 - c10) * fy;
        float v   = b0  + (b1  - b0 ) * fx;

        sdf_out[(size_t)b * N + n] = v;
        val = v * v;
    }

    #pragma unroll
    for (int off = 32; off > 0; off >>= 1) val += __shfl_down(val, off, 64);
    __shared__ float sm[4];
    int lane = threadIdx.x & 63, wid = threadIdx.x >> 6;
    if (lane == 0) sm[wid] = val;
    __syncthreads();
    if (threadIdx.x == 0)
        partials[(size_t)b * gridDim.x + blockIdx.x] = sm[0] + sm[1] + sm[2] + sm[3];
}

// ---------------- Tier C: fp16 grid in 2x2x8 bricks (64B lines) ----------------
// ushort element index for grid point (x,y,z):
//   ((x>>1)<<17) | ((y>>1)<<10) | ((z>>3)<<5) | ((x&1)<<4) | ((y&1)<<3) | (z&7)
__global__ __launch_bounds__(256)
void pack_c(const float* __restrict__ g, ushort* __restrict__ tbl)
{
    int L = blockIdx.x * 256 + threadIdx.x;     // < 128*128*32 lines
    int Z = L & 31, Y = (L >> 5) & 127, X = L >> 12;
    int xb = X << 1, yb = Y << 1, zb = Z << 3;
    ushort h[32];
    #pragma unroll
    for (int dx = 0; dx < 2; dx++)
        #pragma unroll
        for (int dy = 0; dy < 2; dy++) {
            const float* p = g + (((xb + dx) << 16) | ((yb + dy) << 8) | zb);
            #pragma unroll
            for (int dz = 0; dz < 8; dz++) {
                __half v = __float2half_rn(p[dz]);
                h[(dx << 4) + (dy << 3) + dz] = *(ushort*)&v;
            }
        }
    uint4* o = (uint4*)(tbl + ((size_t)L << 5));
    const uint4* s = (const uint4*)h;
    o[0] = s[0]; o[1] = s[1]; o[2] = s[2]; o[3] = s[3];
}

__device__ __forceinline__ int brick_idx(int x, int y, int z) {
    return ((x >> 1) << 17) | ((y >> 1) << 10) | ((z >> 3) << 5)
         | ((x & 1) << 4) | ((y & 1) << 3) | (z & 7);
}

__global__ __launch_bounds__(256)
void sdf_c(const ushort* __restrict__ tbl,
           const float* __restrict__ limits,
           const float* __restrict__ points,
           const float* __restrict__ rt,
           float* __restrict__ sdf_out,
           float* __restrict__ partials,
           int N)
{
    const int b = blockIdx.y;
    const int n = blockIdx.x * 256 + threadIdx.x;

    const float* m = rt + b * 12;
    float m00=m[0], m01=m[1], m02=m[2],  m03=m[3];
    float m10=m[4], m11=m[5], m12=m[6],  m13=m[7];
    float m20=m[8], m21=m[9], m22=m[10], m23=m[11];
    float lo0=limits[0], lo1=limits[1], lo2=limits[2];
    float hi0=limits[3], hi1=limits[4], hi2=limits[5];
    float s0 = 255.0f/(hi0-lo0), s1 = 255.0f/(hi1-lo1), s2 = 255.0f/(hi2-lo2);

    float val = 0.0f;
    if (n < N) {
        float px = points[n*3+0], py = points[n*3+1], pz = points[n*3+2];
        float x = m00*px + m01*py + m02*pz + m03;
        float y = m10*px + m11*py + m12*pz + m13;
        float z = m20*px + m21*py + m22*pz + m23;
        float u0 = fminf(fmaxf((x - lo0) * s0, 0.f), 254.9999f);
        float u1 = fminf(fmaxf((y - lo1) * s1, 0.f), 254.9999f);
        float u2 = fminf(fmaxf((z - lo2) * s2, 0.f), 254.9999f);
        int x0 = (int)u0, y0 = (int)u1, z0 = (int)u2;
        float fx = u0 - (float)x0, fy = u1 - (float)y0, fz = u2 - (float)z0;
        int x1 = x0 + 1, y1 = y0 + 1, z1 = z0 + 1;   // <= 255 always

        float g000 = __half2float(*(const __half*)&tbl[brick_idx(x0,y0,z0)]);
        float g100 = __half2float(*(const __half*)&tbl[brick_idx(x1,y0,z0)]);
        float g010 = __half2float(*(const __half*)&tbl[brick_idx(x0,y1,z0)]);
        float g110 = __half2float(*(const __half*)&tbl[brick_idx(x1,y1,z0)]);
        float g001 = __half2float(*(const __half*)&tbl[brick_idx(x0,y0,z1)]);
        float g101 = __half2float(*(const __half*)&tbl[brick_idx(x1,y0,z1)]);
        float g011 = __half2float(*(const __half*)&tbl[brick_idx(x0,y1,z1)]);
        float g111 = __half2float(*(const __half*)&tbl[brick_idx(x1,y1,z1)]);

        float c00 = g000*(1.f-fx) + g100*fx;
        float c10 = g010*(1.f-fx) + g110*fx;
        float c01 = g001*(1.f-fx) + g101*fx;
        float c11 = g011*(1.f-fx) + g111*fx;
        float c0  = c00*(1.f-fy) + c10*fy;
        float c1  = c01*(1.f-fy) + c11*fy;
        float v   = c0*(1.f-fz) + c1*fz;

        sdf_out[(size_t)b * N + n] = v;
        val = v * v;
    }

    #pragma unroll
    for (int off = 32; off > 0; off >>= 1) val += __shfl_down(val, off, 64);
    __shared__ float sm[4];
    int lane = threadIdx.x & 63, wid = threadIdx.x >> 6;
    if (lane == 0) sm[wid] = val;
    __syncthreads();
    if (threadIdx.x == 0)
        partials[(size_t)b * gridDim.x + blockIdx.x] = sm[0] + sm[1] + sm[2] + sm[3];
}

__global__ __launch_bounds__(1024)
void reduce_kernel(const float* __restrict__ partials, int n, float* __restrict__ out)
{
    float s = 0.f;
    for (int i = threadIdx.x; i < n; i += 1024) s += partials[i];
    #pragma unroll
    for (int off = 32; off > 0; off >>= 1) s += __shfl_down(s, off, 64);
    __shared__ float sm[16];
    int lane = threadIdx.x & 63, wid = threadIdx.x >> 6;
    if (lane == 0) sm[wid] = s;
    __syncthreads();
    if (threadIdx.x == 0) {
        float t = 0.f;
        #pragma unroll
        for (int i = 0; i < 16; i++) t += sm[i];
        out[0] = 0.5f * t;
    }
}

// ---------------- Fallback: direct fp32, atomic loss ----------------
__global__ __launch_bounds__(256)
void sdf_kernel(const float* __restrict__ grid,
                const float* __restrict__ limits,
                const float* __restrict__ points,
                const float* __restrict__ rt,
                float* __restrict__ out, int N)
{
    const int b = blockIdx.y;
    const int n = blockIdx.x * 256 + threadIdx.x;
    const float* m = rt + b * 12;
    float m00=m[0], m01=m[1], m02=m[2],  m03=m[3];
    float m10=m[4], m11=m[5], m12=m[6],  m13=m[7];
    float m20=m[8], m21=m[9], m22=m[10], m23=m[11];
    float lo0=limits[0], lo1=limits[1], lo2=limits[2];
    float hi0=limits[3], hi1=limits[4], hi2=limits[5];
    float s0 = 255.0f/(hi0-lo0), s1 = 255.0f/(hi1-lo1), s2 = 255.0f/(hi2-lo2);

    float val = 0.0f;
    if (n < N) {
        float px = points[n*3+0], py = points[n*3+1], pz = points[n*3+2];
        float x = m00*px + m01*py + m02*pz + m03;
        float y = m10*px + m11*py + m12*pz + m13;
        float z = m20*px + m21*py + m22*pz + m23;
        float u0 = fminf(fmaxf((x - lo0) * s0, 0.f), 254.9999f);
        float u1 = fminf(fmaxf((y - lo1) * s1, 0.f), 254.9999f);
        float u2 = fminf(fmaxf((z - lo2) * s2, 0.f), 254.9999f);
        int x0 = (int)u0, y0 = (int)u1, z0 = (int)u2;
        float fx = u0 - (float)x0, fy = u1 - (float)y0, fz = u2 - (float)z0;
        int x1 = x0 + 1, y1 = y0 + 1, z1 = z0 + 1;
        int bx0 = x0 << 16, bx1 = x1 << 16;
        int by0 = y0 << 8,  by1 = y1 << 8;
        float g000 = grid[bx0|by0|z0], g100 = grid[bx1|by0|z0];
        float g010 = grid[bx0|by1|z0], g110 = grid[bx1|by1|z0];
        float g001 = grid[bx0|by0|z1], g101 = grid[bx1|by0|z1];
        float g011 = grid[bx0|by1|z1], g111 = grid[bx1|by1|z1];
        float c00 = g000*(1.f-fx) + g100*fx;
        float c10 = g010*(1.f-fx) + g110*fx;
        float c01 = g001*(1.f-fx) + g101*fx;
        float c11 = g011*(1.f-fx) + g111*fx;
        float c0  = c00*(1.f-fy) + c10*fy;
        float c1  = c01*(1.f-fy) + c11*fy;
        float v   = c0*(1.f-fz) + c1*fz;
        out[1 + (size_t)b * N + n] = v;
        val = v * v;
    }
    #pragma unroll
    for (int off = 32; off > 0; off >>= 1) val += __shfl_down(val, off, 64);
    __shared__ float sm[4];
    int lane = threadIdx.x & 63, wid = threadIdx.x >> 6;
    if (lane == 0) sm[wid] = val;
    __syncthreads();
    if (threadIdx.x == 0)
        atomicAdd(out, 0.5f * (sm[0] + sm[1] + sm[2] + sm[3]));
}

extern "C" void kernel_launch(void* const* d_in, const int* in_sizes, int n_in,
                              void* d_out, int out_size, void* d_ws, size_t ws_size,
                              hipStream_t stream) {
    const float* pose_delta = (const float*)d_in[0];
    const float* pose_init  = (const float*)d_in[1];
    const float* grid       = (const float*)d_in[2];
    const float* limits     = (const float*)d_in[3];
    const float* points     = (const float*)d_in[4];
    float* out = (float*)d_out;

    int B = in_sizes[0] / 6;
    int N = in_sizes[4] / 3;
    long long se3_off = 1 + (long long)B * N;

    const size_t TBL_OFF = 131072;                       // 128KB
    const size_t needA = TBL_OFF + (size_t)255 * 65536 * 16;   // ~255.1MB
    const size_t needC = TBL_OFF + ((size_t)1 << 25);          // 32MB + 128KB
    float* rt       = (float*)d_ws;
    float* partials = (float*)((char*)d_ws + 4096);
    void*  tbl      = (void*)((char*)d_ws + TBL_OFF);

    pose_kernel<<<1, ((B + 63) / 64) * 64, 0, stream>>>(pose_delta, pose_init, out, rt, B, se3_off);

    bool g256 = (in_sizes[2] == (1 << 24));
    dim3 g((N + 255) / 256, B);
    int nPart = B * (int)g.x;   // <= ~25k floats, fits [4KB,128KB)

    if (g256 && ws_size >= needA) {
        pack_a<<<255 * 65536 / 256, 256, 0, stream>>>(grid, (uint4*)tbl);
        sdf_a<<<g, 256, 0, stream>>>((const uint4*)tbl, limits, points, rt, out + 1, partials, N);
        reduce_kernel<<<1, 1024, 0, stream>>>(partials, nPart, out);
    } else if (g256 && ws_size >= needC) {
        pack_c<<<128 * 128 * 32 / 256, 256, 0, stream>>>(grid, (ushort*)tbl);
        sdf_c<<<g, 256, 0, stream>>>((const ushort*)tbl, limits, points, rt, out + 1, partials, N);
        reduce_kernel<<<1, 1024, 0, stream>>>(partials, nPart, out);
    } else {
        sdf_kernel<<<g, 256, 0, stream>>>(grid, limits, points, rt, out, N);
    }
}

// Round 4
// 181.733 us; speedup vs baseline: 2.1970x; 1.0359x over previous
//
#include <hip/hip_runtime.h>
#include <hip/hip_fp16.h>
#include <math.h>

// SDF loss: out = [loss(1), sdf_values(B*N), se3(B*16)]  (float32)
// G fixed at 256: flat grid index = (x<<16)|(y<<8)|z.
// u clamped to <= 254.9999 so x0,y0,z0 <= 254; min(i0+1,255) never binds.
//
// ws layout: [0,4KB) rt | [4KB,128KB) partials | [128KB, +255MB) table
// Tier A: fp16x8 corner table (255*65536 entries * 16B), ONE dwordx4 gather
//         per (point,pose). sdf_a4 processes 4 poses per thread for 4x MLP.

__global__ void pose_kernel(const float* __restrict__ pose_delta,  // B*6
                            const float* __restrict__ pose_init,   // B*16
                            float* __restrict__ out,               // d_out
                            float* __restrict__ rt,                // ws: B*12
                            int B, long long se3_off)
{
    int b = blockIdx.x * blockDim.x + threadIdx.x;
    if (b == 0) out[0] = 0.0f;   // for fallback (atomic) path; overwritten by reduce in fast paths
    if (b >= B) return;

    const float* d = pose_delta + b * 6;
    float ux = d[0], uy = d[1], uz = d[2];
    float wx = d[3], wy = d[4], wz = d[5];
    float th2 = wx*wx + wy*wy + wz*wz;
    float th  = sqrtf(th2);
    float A, Bc, Cc;
    if (th < 1e-6f) {
        A  = 1.0f - th2 * (1.0f/6.0f);
        Bc = 0.5f - th2 * (1.0f/24.0f);
        Cc = (1.0f/6.0f) - th2 * (1.0f/120.0f);
    } else {
        float sn = sinf(th), cs = cosf(th);
        A  = sn / th;
        Bc = (1.0f - cs) / th2;
        Cc = (th - sn) / (th2 * th);
    }
    float K[3][3]  = {{0.f,-wz,wy},{wz,0.f,-wx},{-wy,wx,0.f}};
    float K2[3][3];
    #pragma unroll
    for (int i = 0; i < 3; i++)
        #pragma unroll
        for (int j = 0; j < 3; j++) {
            float s = 0.f;
            #pragma unroll
            for (int k = 0; k < 3; k++) s += K[i][k] * K[k][j];
            K2[i][j] = s;
        }
    float R[3][3], V[3][3];
    #pragma unroll
    for (int i = 0; i < 3; i++)
        #pragma unroll
        for (int j = 0; j < 3; j++) {
            float I = (i == j) ? 1.f : 0.f;
            R[i][j] = I + A  * K[i][j] + Bc * K2[i][j];
            V[i][j] = I + Bc * K[i][j] + Cc * K2[i][j];
        }
    float tt[3];
    #pragma unroll
    for (int i = 0; i < 3; i++)
        tt[i] = V[i][0]*ux + V[i][1]*uy + V[i][2]*uz;

    const float* P = pose_init + b * 16;
    float M[3][4];
    #pragma unroll
    for (int i = 0; i < 3; i++)
        #pragma unroll
        for (int j = 0; j < 4; j++)
            M[i][j] = R[i][0]*P[0*4+j] + R[i][1]*P[1*4+j] + R[i][2]*P[2*4+j] + tt[i]*P[3*4+j];

    float* o = out + se3_off + (long long)b * 16;
    #pragma unroll
    for (int i = 0; i < 3; i++)
        #pragma unroll
        for (int j = 0; j < 4; j++) o[i*4+j] = M[i][j];
    o[12] = P[12]; o[13] = P[13]; o[14] = P[14]; o[15] = P[15];

    float* r = rt + b * 12;
    #pragma unroll
    for (int i = 0; i < 3; i++) {
        r[i*4+0] = M[i][0]; r[i*4+1] = M[i][1];
        r[i*4+2] = M[i][2]; r[i*4+3] = M[i][3];
    }
}

// ---------------- Tier A: fp16x8 corner table ----------------
// tbl[(x<<16)|(y<<8)|z], x in [0,254]. Entry: .x=(e000,e001) .y=(e010,e011)
// .z=(e100,e101) .w=(e110,e111), pairs packed low=z0 high=z1.
__global__ __launch_bounds__(256)
void pack_a(const float* __restrict__ g, uint4* __restrict__ tbl)
{
    int idx = blockIdx.x * 256 + threadIdx.x;   // < 255*65536, x = idx>>16 <= 254
    int z = idx & 255, y = (idx >> 8) & 255;
    int ys = (y < 255) ? 256 : 0;
    int zs = (z < 255) ? 1   : 0;
    const float* p = g + idx;
    float e000 = p[0],          e001 = p[zs];
    float e010 = p[ys],         e011 = p[ys + zs];
    float e100 = p[65536],      e101 = p[65536 + zs];
    float e110 = p[65536 + ys], e111 = p[65536 + ys + zs];
    uint4 u;
    __half2 h;
    h = __floats2half2_rn(e000, e001); u.x = *(unsigned int*)&h;
    h = __floats2half2_rn(e010, e011); u.y = *(unsigned int*)&h;
    h = __floats2half2_rn(e100, e101); u.z = *(unsigned int*)&h;
    h = __floats2half2_rn(e110, e111); u.w = *(unsigned int*)&h;
    tbl[idx] = u;
}

// 4 poses per thread: 4 independent gathers in flight (MLP x4).
__global__ __launch_bounds__(256)
void sdf_a4(const uint4* __restrict__ tbl,
            const float* __restrict__ limits,
            const float* __restrict__ points,
            const float* __restrict__ rt,
            float* __restrict__ sdf_out,     // out+1
            float* __restrict__ partials,    // ws+4KB
            int N, int B)
{
    const int bg = blockIdx.y;       // pose group
    const int b0 = bg * 4;
    const int n  = blockIdx.x * 256 + threadIdx.x;

    // 4 pose rows, block-uniform (scalarized)
    float M[4][12];
    #pragma unroll
    for (int bb = 0; bb < 4; bb++) {
        int b = min(b0 + bb, B - 1);
        const float* m = rt + b * 12;
        #pragma unroll
        for (int j = 0; j < 12; j++) M[bb][j] = m[j];
    }
    float lo0=limits[0], lo1=limits[1], lo2=limits[2];
    float hi0=limits[3], hi1=limits[4], hi2=limits[5];
    float s0 = 255.0f/(hi0-lo0), s1 = 255.0f/(hi1-lo1), s2 = 255.0f/(hi2-lo2);

    float val = 0.0f;
    if (n < N) {
        float px = points[n*3+0], py = points[n*3+1], pz = points[n*3+2];

        int   idx[4];
        float fx[4], fy[4], fz[4];
        #pragma unroll
        for (int bb = 0; bb < 4; bb++) {
            float x = M[bb][0]*px + M[bb][1]*py + M[bb][2]*pz  + M[bb][3];
            float y = M[bb][4]*px + M[bb][5]*py + M[bb][6]*pz  + M[bb][7];
            float z = M[bb][8]*px + M[bb][9]*py + M[bb][10]*pz + M[bb][11];
            float u0 = fminf(fmaxf((x - lo0) * s0, 0.f), 254.9999f);
            float u1 = fminf(fmaxf((y - lo1) * s1, 0.f), 254.9999f);
            float u2 = fminf(fmaxf((z - lo2) * s2, 0.f), 254.9999f);
            int x0 = (int)u0, y0 = (int)u1, z0 = (int)u2;
            fx[bb] = u0 - (float)x0;
            fy[bb] = u1 - (float)y0;
            fz[bb] = u2 - (float)z0;
            idx[bb] = (x0 << 16) | (y0 << 8) | z0;
        }

        uint4 u[4];
        #pragma unroll
        for (int bb = 0; bb < 4; bb++) u[bb] = tbl[idx[bb]];   // 4 independent gathers

        #pragma unroll
        for (int bb = 0; bb < 4; bb++) {
            float2 f00 = __half22float2(*(__half2*)&u[bb].x);
            float2 f01 = __half22float2(*(__half2*)&u[bb].y);
            float2 f10 = __half22float2(*(__half2*)&u[bb].z);
            float2 f11 = __half22float2(*(__half2*)&u[bb].w);
            float c00 = f00.x + (f00.y - f00.x) * fz[bb];
            float c01 = f01.x + (f01.y - f01.x) * fz[bb];
            float c10 = f10.x + (f10.y - f10.x) * fz[bb];
            float c11 = f11.x + (f11.y - f11.x) * fz[bb];
            float b0l = c00 + (c01 - c00) * fy[bb];
            float b1l = c10 + (c11 - c10) * fy[bb];
            float v   = b0l + (b1l - b0l) * fx[bb];
            if (b0 + bb < B) {
                sdf_out[(size_t)(b0 + bb) * N + n] = v;
                val += v * v;
            }
        }
    }

    #pragma unroll
    for (int off = 32; off > 0; off >>= 1) val += __shfl_down(val, off, 64);
    __shared__ float sm[4];
    int lane = threadIdx.x & 63, wid = threadIdx.x >> 6;
    if (lane == 0) sm[wid] = val;
    __syncthreads();
    if (threadIdx.x == 0)
        partials[(size_t)bg * gridDim.x + blockIdx.x] = sm[0] + sm[1] + sm[2] + sm[3];
}

__global__ __launch_bounds__(1024)
void reduce_kernel(const float* __restrict__ partials, int n, float* __restrict__ out)
{
    float s = 0.f;
    for (int i = threadIdx.x; i < n; i += 1024) s += partials[i];
    #pragma unroll
    for (int off = 32; off > 0; off >>= 1) s += __shfl_down(s, off, 64);
    __shared__ float sm[16];
    int lane = threadIdx.x & 63, wid = threadIdx.x >> 6;
    if (lane == 0) sm[wid] = s;
    __syncthreads();
    if (threadIdx.x == 0) {
        float t = 0.f;
        #pragma unroll
        for (int i = 0; i < 16; i++) t += sm[i];
        out[0] = 0.5f * t;
    }
}

// ---------------- Fallback: direct fp32, atomic loss ----------------
__global__ __launch_bounds__(256)
void sdf_kernel(const float* __restrict__ grid,
                const float* __restrict__ limits,
                const float* __restrict__ points,
                const float* __restrict__ rt,
                float* __restrict__ out, int N)
{
    const int b = blockIdx.y;
    const int n = blockIdx.x * 256 + threadIdx.x;
    const float* m = rt + b * 12;
    float m00=m[0], m01=m[1], m02=m[2],  m03=m[3];
    float m10=m[4], m11=m[5], m12=m[6],  m13=m[7];
    float m20=m[8], m21=m[9], m22=m[10], m23=m[11];
    float lo0=limits[0], lo1=limits[1], lo2=limits[2];
    float hi0=limits[3], hi1=limits[4], hi2=limits[5];
    float s0 = 255.0f/(hi0-lo0), s1 = 255.0f/(hi1-lo1), s2 = 255.0f/(hi2-lo2);

    float val = 0.0f;
    if (n < N) {
        float px = points[n*3+0], py = points[n*3+1], pz = points[n*3+2];
        float x = m00*px + m01*py + m02*pz + m03;
        float y = m10*px + m11*py + m12*pz + m13;
        float z = m20*px + m21*py + m22*pz + m23;
        float u0 = fminf(fmaxf((x - lo0) * s0, 0.f), 254.9999f);
        float u1 = fminf(fmaxf((y - lo1) * s1, 0.f), 254.9999f);
        float u2 = fminf(fmaxf((z - lo2) * s2, 0.f), 254.9999f);
        int x0 = (int)u0, y0 = (int)u1, z0 = (int)u2;
        float fx = u0 - (float)x0, fy = u1 - (float)y0, fz = u2 - (float)z0;
        int x1 = x0 + 1, y1 = y0 + 1, z1 = z0 + 1;
        int bx0 = x0 << 16, bx1 = x1 << 16;
        int by0 = y0 << 8,  by1 = y1 << 8;
        float g000 = grid[bx0|by0|z0], g100 = grid[bx1|by0|z0];
        float g010 = grid[bx0|by1|z0], g110 = grid[bx1|by1|z0];
        float g001 = grid[bx0|by0|z1], g101 = grid[bx1|by0|z1];
        float g011 = grid[bx0|by1|z1], g111 = grid[bx1|by1|z1];
        float c00 = g000*(1.f-fx) + g100*fx;
        float c10 = g010*(1.f-fx) + g110*fx;
        float c01 = g001*(1.f-fx) + g101*fx;
        float c11 = g011*(1.f-fx) + g111*fx;
        float c0  = c00*(1.f-fy) + c10*fy;
        float c1  = c01*(1.f-fy) + c11*fy;
        float v   = c0*(1.f-fz) + c1*fz;
        out[1 + (size_t)b * N + n] = v;
        val = v * v;
    }
    #pragma unroll
    for (int off = 32; off > 0; off >>= 1) val += __shfl_down(val, off, 64);
    __shared__ float sm[4];
    int lane = threadIdx.x & 63, wid = threadIdx.x >> 6;
    if (lane == 0) sm[wid] = val;
    __syncthreads();
    if (threadIdx.x == 0)
        atomicAdd(out, 0.5f * (sm[0] + sm[1] + sm[2] + sm[3]));
}

extern "C" void kernel_launch(void* const* d_in, const int* in_sizes, int n_in,
                              void* d_out, int out_size, void* d_ws, size_t ws_size,
                              hipStream_t stream) {
    const float* pose_delta = (const float*)d_in[0];
    const float* pose_init  = (const float*)d_in[1];
    const float* grid       = (const float*)d_in[2];
    const float* limits     = (const float*)d_in[3];
    const float* points     = (const float*)d_in[4];
    float* out = (float*)d_out;

    int B = in_sizes[0] / 6;
    int N = in_sizes[4] / 3;
    long long se3_off = 1 + (long long)B * N;

    const size_t TBL_OFF = 131072;                             // 128KB
    const size_t needA = TBL_OFF + (size_t)255 * 65536 * 16;   // ~255.1MB
    float* rt       = (float*)d_ws;
    float* partials = (float*)((char*)d_ws + 4096);
    void*  tbl      = (void*)((char*)d_ws + TBL_OFF);

    pose_kernel<<<1, ((B + 63) / 64) * 64, 0, stream>>>(pose_delta, pose_init, out, rt, B, se3_off);

    bool g256 = (in_sizes[2] == (1 << 24));
    int gridX = (N + 255) / 256;

    if (g256 && ws_size >= needA) {
        int nBG = (B + 3) / 4;
        pack_a<<<255 * 65536 / 256, 256, 0, stream>>>(grid, (uint4*)tbl);
        dim3 g(gridX, nBG);
        sdf_a4<<<g, 256, 0, stream>>>((const uint4*)tbl, limits, points, rt,
                                      out + 1, partials, N, B);
        reduce_kernel<<<1, 1024, 0, stream>>>(partials, nBG * gridX, out);
    } else {
        dim3 g(gridX, B);
        sdf_kernel<<<g, 256, 0, stream>>>(grid, limits, points, rt, out, N);
    }
}

// Round 5
// 150.118 us; speedup vs baseline: 2.6597x; 1.2106x over previous
//
#include <hip/hip_runtime.h>
#include <hip/hip_fp16.h>
#include <math.h>

// SDF loss: out = [loss(1), sdf_values(B*N), se3(B*16)]  (float32)
// G fixed at 256: flat grid index = (x<<16)|(y<<8)|z.
// u clamped to <= 254.9999 so x0,y0,z0 <= 254; min(i0+1,255) never binds.
//
// ws layout: [0,4KB) rt | [4KB,128KB) partials | [128KB, +127.5MB) table
// Z-plane table: entry e(x,y,z) = fp16x4 xy-cell corners in plane z:
//   .x = half2( g(x,y,z),   g(x+1,y,z)   )
//   .y = half2( g(x,y+1,z), g(x+1,y+1,z) )
// A sample reads entries z0 and z0+1 (16 contiguous bytes, one line 7/8 of
// the time). One pose-quad per thread = 4x MLP.

__global__ void pose_kernel(const float* __restrict__ pose_delta,  // B*6
                            const float* __restrict__ pose_init,   // B*16
                            float* __restrict__ out,               // d_out
                            float* __restrict__ rt,                // ws: B*12
                            int B, long long se3_off)
{
    int b = blockIdx.x * blockDim.x + threadIdx.x;
    if (b == 0) out[0] = 0.0f;   // for fallback (atomic) path; fast path overwrites via reduce
    if (b >= B) return;

    const float* d = pose_delta + b * 6;
    float ux = d[0], uy = d[1], uz = d[2];
    float wx = d[3], wy = d[4], wz = d[5];
    float th2 = wx*wx + wy*wy + wz*wz;
    float th  = sqrtf(th2);
    float A, Bc, Cc;
    if (th < 1e-6f) {
        A  = 1.0f - th2 * (1.0f/6.0f);
        Bc = 0.5f - th2 * (1.0f/24.0f);
        Cc = (1.0f/6.0f) - th2 * (1.0f/120.0f);
    } else {
        float sn = sinf(th), cs = cosf(th);
        A  = sn / th;
        Bc = (1.0f - cs) / th2;
        Cc = (th - sn) / (th2 * th);
    }
    float K[3][3]  = {{0.f,-wz,wy},{wz,0.f,-wx},{-wy,wx,0.f}};
    float K2[3][3];
    #pragma unroll
    for (int i = 0; i < 3; i++)
        #pragma unroll
        for (int j = 0; j < 3; j++) {
            float s = 0.f;
            #pragma unroll
            for (int k = 0; k < 3; k++) s += K[i][k] * K[k][j];
            K2[i][j] = s;
        }
    float R[3][3], V[3][3];
    #pragma unroll
    for (int i = 0; i < 3; i++)
        #pragma unroll
        for (int j = 0; j < 3; j++) {
            float I = (i == j) ? 1.f : 0.f;
            R[i][j] = I + A  * K[i][j] + Bc * K2[i][j];
            V[i][j] = I + Bc * K[i][j] + Cc * K2[i][j];
        }
    float tt[3];
    #pragma unroll
    for (int i = 0; i < 3; i++)
        tt[i] = V[i][0]*ux + V[i][1]*uy + V[i][2]*uz;

    const float* P = pose_init + b * 16;
    float M[3][4];
    #pragma unroll
    for (int i = 0; i < 3; i++)
        #pragma unroll
        for (int j = 0; j < 4; j++)
            M[i][j] = R[i][0]*P[0*4+j] + R[i][1]*P[1*4+j] + R[i][2]*P[2*4+j] + tt[i]*P[3*4+j];

    float* o = out + se3_off + (long long)b * 16;
    #pragma unroll
    for (int i = 0; i < 3; i++)
        #pragma unroll
        for (int j = 0; j < 4; j++) o[i*4+j] = M[i][j];
    o[12] = P[12]; o[13] = P[13]; o[14] = P[14]; o[15] = P[15];

    float* r = rt + b * 12;
    #pragma unroll
    for (int i = 0; i < 3; i++) {
        r[i*4+0] = M[i][0]; r[i*4+1] = M[i][1];
        r[i*4+2] = M[i][2]; r[i*4+3] = M[i][3];
    }
}

// ---------------- Z-plane table pack: 255*65536 entries * 8B = 127.5MB -------
__global__ __launch_bounds__(256)
void pack_zp(const float* __restrict__ g, uint2* __restrict__ tbl)
{
    int idx = blockIdx.x * 256 + threadIdx.x;   // x = idx>>16 in [0,254]
    int y = (idx >> 8) & 255;
    int ys = (y < 255) ? 256 : 0;               // y=255 entries never read; avoid OOB
    const float* p = g + idx;                   // x+1 <= 255 always (x <= 254)
    float e00 = p[0],          e10 = p[65536];
    float e01 = p[ys],         e11 = p[65536 + ys];
    uint2 u;
    __half2 h;
    h = __floats2half2_rn(e00, e10); u.x = *(unsigned int*)&h;
    h = __floats2half2_rn(e01, e11); u.y = *(unsigned int*)&h;
    tbl[idx] = u;
}

// 4 poses per thread; per sample: two 8B loads (z0, z0+1), same 64B line 7/8.
__global__ __launch_bounds__(256)
void sdf_zp4(const uint2* __restrict__ tbl,
             const float* __restrict__ limits,
             const float* __restrict__ points,
             const float* __restrict__ rt,
             float* __restrict__ sdf_out,     // out+1
             float* __restrict__ partials,    // ws+4KB
             int N, int B)
{
    const int bg = blockIdx.y;       // pose group
    const int b0 = bg * 4;
    const int n  = blockIdx.x * 256 + threadIdx.x;

    float M[4][12];
    #pragma unroll
    for (int bb = 0; bb < 4; bb++) {
        int b = min(b0 + bb, B - 1);
        const float* m = rt + b * 12;
        #pragma unroll
        for (int j = 0; j < 12; j++) M[bb][j] = m[j];
    }
    float lo0=limits[0], lo1=limits[1], lo2=limits[2];
    float hi0=limits[3], hi1=limits[4], hi2=limits[5];
    float s0 = 255.0f/(hi0-lo0), s1 = 255.0f/(hi1-lo1), s2 = 255.0f/(hi2-lo2);

    float val = 0.0f;
    if (n < N) {
        float px = points[n*3+0], py = points[n*3+1], pz = points[n*3+2];

        int   idx[4];
        float fx[4], fy[4], fz[4];
        #pragma unroll
        for (int bb = 0; bb < 4; bb++) {
            float x = M[bb][0]*px + M[bb][1]*py + M[bb][2]*pz  + M[bb][3];
            float y = M[bb][4]*px + M[bb][5]*py + M[bb][6]*pz  + M[bb][7];
            float z = M[bb][8]*px + M[bb][9]*py + M[bb][10]*pz + M[bb][11];
            float u0 = fminf(fmaxf((x - lo0) * s0, 0.f), 254.9999f);
            float u1 = fminf(fmaxf((y - lo1) * s1, 0.f), 254.9999f);
            float u2 = fminf(fmaxf((z - lo2) * s2, 0.f), 254.9999f);
            int x0 = (int)u0, y0 = (int)u1, z0 = (int)u2;
            fx[bb] = u0 - (float)x0;
            fy[bb] = u1 - (float)y0;
            fz[bb] = u2 - (float)z0;
            idx[bb] = (x0 << 16) | (y0 << 8) | z0;
        }

        // 8 independent 8B gathers (4 line-pairs) in flight
        uint2 e0[4], e1[4];
        #pragma unroll
        for (int bb = 0; bb < 4; bb++) {
            e0[bb] = tbl[idx[bb]];
            e1[bb] = tbl[idx[bb] + 1];
        }

        #pragma unroll
        for (int bb = 0; bb < 4; bb++) {
            float2 a00 = __half22float2(*(__half2*)&e0[bb].x);  // (e00,e10) @ z0
            float2 a01 = __half22float2(*(__half2*)&e0[bb].y);  // (e01,e11) @ z0
            float2 b00 = __half22float2(*(__half2*)&e1[bb].x);  // @ z1
            float2 b01 = __half22float2(*(__half2*)&e1[bb].y);
            float c0 = a00.x + (a00.y - a00.x) * fx[bb];
            float c1 = a01.x + (a01.y - a01.x) * fx[bb];
            float p0 = c0 + (c1 - c0) * fy[bb];                 // plane z0
            float d0 = b00.x + (b00.y - b00.x) * fx[bb];
            float d1 = b01.x + (b01.y - b01.x) * fx[bb];
            float p1 = d0 + (d1 - d0) * fy[bb];                 // plane z1
            float v  = p0 + (p1 - p0) * fz[bb];
            if (b0 + bb < B) {
                sdf_out[(size_t)(b0 + bb) * N + n] = v;
                val += v * v;
            }
        }
    }

    #pragma unroll
    for (int off = 32; off > 0; off >>= 1) val += __shfl_down(val, off, 64);
    __shared__ float sm[4];
    int lane = threadIdx.x & 63, wid = threadIdx.x >> 6;
    if (lane == 0) sm[wid] = val;
    __syncthreads();
    if (threadIdx.x == 0)
        partials[(size_t)bg * gridDim.x + blockIdx.x] = sm[0] + sm[1] + sm[2] + sm[3];
}

__global__ __launch_bounds__(1024)
void reduce_kernel(const float* __restrict__ partials, int n, float* __restrict__ out)
{
    float s = 0.f;
    for (int i = threadIdx.x; i < n; i += 1024) s += partials[i];
    #pragma unroll
    for (int off = 32; off > 0; off >>= 1) s += __shfl_down(s, off, 64);
    __shared__ float sm[16];
    int lane = threadIdx.x & 63, wid = threadIdx.x >> 6;
    if (lane == 0) sm[wid] = s;
    __syncthreads();
    if (threadIdx.x == 0) {
        float t = 0.f;
        #pragma unroll
        for (int i = 0; i < 16; i++) t += sm[i];
        out[0] = 0.5f * t;
    }
}

// ---------------- Fallback: direct fp32, atomic loss ----------------
__global__ __launch_bounds__(256)
void sdf_kernel(const float* __restrict__ grid,
                const float* __restrict__ limits,
                const float* __restrict__ points,
                const float* __restrict__ rt,
                float* __restrict__ out, int N)
{
    const int b = blockIdx.y;
    const int n = blockIdx.x * 256 + threadIdx.x;
    const float* m = rt + b * 12;
    float m00=m[0], m01=m[1], m02=m[2],  m03=m[3];
    float m10=m[4], m11=m[5], m12=m[6],  m13=m[7];
    float m20=m[8], m21=m[9], m22=m[10], m23=m[11];
    float lo0=limits[0], lo1=limits[1], lo2=limits[2];
    float hi0=limits[3], hi1=limits[4], hi2=limits[5];
    float s0 = 255.0f/(hi0-lo0), s1 = 255.0f/(hi1-lo1), s2 = 255.0f/(hi2-lo2);

    float val = 0.0f;
    if (n < N) {
        float px = points[n*3+0], py = points[n*3+1], pz = points[n*3+2];
        float x = m00*px + m01*py + m02*pz + m03;
        float y = m10*px + m11*py + m12*pz + m13;
        float z = m20*px + m21*py + m22*pz + m23;
        float u0 = fminf(fmaxf((x - lo0) * s0, 0.f), 254.9999f);
        float u1 = fminf(fmaxf((y - lo1) * s1, 0.f), 254.9999f);
        float u2 = fminf(fmaxf((z - lo2) * s2, 0.f), 254.9999f);
        int x0 = (int)u0, y0 = (int)u1, z0 = (int)u2;
        float fx = u0 - (float)x0, fy = u1 - (float)y0, fz = u2 - (float)z0;
        int x1 = x0 + 1, y1 = y0 + 1, z1 = z0 + 1;
        int bx0 = x0 << 16, bx1 = x1 << 16;
        int by0 = y0 << 8,  by1 = y1 << 8;
        float g000 = grid[bx0|by0|z0], g100 = grid[bx1|by0|z0];
        float g010 = grid[bx0|by1|z0], g110 = grid[bx1|by1|z0];
        float g001 = grid[bx0|by0|z1], g101 = grid[bx1|by0|z1];
        float g011 = grid[bx0|by1|z1], g111 = grid[bx1|by1|z1];
        float c00 = g000*(1.f-fx) + g100*fx;
        float c10 = g010*(1.f-fx) + g110*fx;
        float c01 = g001*(1.f-fx) + g101*fx;
        float c11 = g011*(1.f-fx) + g111*fx;
        float c0  = c00*(1.f-fy) + c10*fy;
        float c1  = c01*(1.f-fy) + c11*fy;
        float v   = c0*(1.f-fz) + c1*fz;
        out[1 + (size_t)b * N + n] = v;
        val = v * v;
    }
    #pragma unroll
    for (int off = 32; off > 0; off >>= 1) val += __shfl_down(val, off, 64);
    __shared__ float sm[4];
    int lane = threadIdx.x & 63, wid = threadIdx.x >> 6;
    if (lane == 0) sm[wid] = val;
    __syncthreads();
    if (threadIdx.x == 0)
        atomicAdd(out, 0.5f * (sm[0] + sm[1] + sm[2] + sm[3]));
}

extern "C" void kernel_launch(void* const* d_in, const int* in_sizes, int n_in,
                              void* d_out, int out_size, void* d_ws, size_t ws_size,
                              hipStream_t stream) {
    const float* pose_delta = (const float*)d_in[0];
    const float* pose_init  = (const float*)d_in[1];
    const float* grid       = (const float*)d_in[2];
    const float* limits     = (const float*)d_in[3];
    const float* points     = (const float*)d_in[4];
    float* out = (float*)d_out;

    int B = in_sizes[0] / 6;
    int N = in_sizes[4] / 3;
    long long se3_off = 1 + (long long)B * N;

    const size_t TBL_OFF = 131072;                                  // 128KB
    const size_t needZP = TBL_OFF + (size_t)255 * 65536 * 8;        // ~127.6MB
    float* rt       = (float*)d_ws;
    float* partials = (float*)((char*)d_ws + 4096);
    void*  tbl      = (void*)((char*)d_ws + TBL_OFF);

    pose_kernel<<<1, ((B + 63) / 64) * 64, 0, stream>>>(pose_delta, pose_init, out, rt, B, se3_off);

    bool g256 = (in_sizes[2] == (1 << 24));
    int gridX = (N + 255) / 256;

    if (g256 && ws_size >= needZP) {
        int nBG = (B + 3) / 4;
        pack_zp<<<255 * 65536 / 256, 256, 0, stream>>>(grid, (uint2*)tbl);
        dim3 g(gridX, nBG);
        sdf_zp4<<<g, 256, 0, stream>>>((const uint2*)tbl, limits, points, rt,
                                       out + 1, partials, N, B);
        reduce_kernel<<<1, 1024, 0, stream>>>(partials, nBG * gridX, out);
    } else {
        dim3 g(gridX, B);
        sdf_kernel<<<g, 256, 0, stream>>>(grid, limits, points, rt, out, N);
    }
}